// Round 1
// baseline (57.436 us; speedup 1.0000x reference)
//
#include <hip/hip_runtime.h>

// HardNMS fused kernel.
// x: [B=16, 2, H=1024, W=1024] f32 -> out: [16, 1, 1024, 1024] f32
// xp   = relu(x[:,1] - x[:,0] - 0.1)
// xNMS = 256 * prod_{8 nbrs} relu(xp - xp_nb)   (zero-padded)
// out  = xp * maxpool3x3(xNMS)                  (xNMS >= 0 so zero-pad == -inf pad)

constexpr int Wd = 1024, Hd = 1024, Bd = 16;
constexpr int TX = 128, TY = 16;
constexpr int RX = TX + 4, RY = TY + 4;   // xp region 132 x 20 (halo 2)
constexpr int NX = TX + 2, NY = TY + 2;   // xNMS region 130 x 18 (halo 1)
constexpr float EPS = 0.1f;

__global__ __launch_bounds__(256, 8) void hardnms_kernel(
    const float* __restrict__ xin, float* __restrict__ out) {
    __shared__ float sxp[RY][RX];
    __shared__ float snm[NY][NX];

    const int x0 = blockIdx.x * TX;
    const int y0 = blockIdx.y * TY;
    const int b  = blockIdx.z;
    const float* __restrict__ p0 = xin + (size_t)(b * 2 + 0) * Hd * Wd;
    const float* __restrict__ p1 = xin + (size_t)(b * 2 + 1) * Hd * Wd;
    const int tid = threadIdx.x;

    // Phase 1: xp into LDS with zero-padded halo of 2.
    for (int idx = tid; idx < RY * RX; idx += 256) {
        const int ry = idx / RX;
        const int rx = idx - ry * RX;
        const int gy = y0 + ry - 2;
        const int gx = x0 + rx - 2;
        float v = 0.f;
        if ((unsigned)gy < (unsigned)Hd && (unsigned)gx < (unsigned)Wd) {
            const size_t o = (size_t)gy * Wd + gx;
            v = fmaxf(p1[o] - p0[o] - EPS, 0.f);
        }
        sxp[ry][rx] = v;
    }
    __syncthreads();

    // Phase 2: xNMS (prod of 8 relu diffs, x256) into LDS, halo of 1.
    for (int idx = tid; idx < NY * NX; idx += 256) {
        const int ny = idx / NX;
        const int nx = idx - ny * NX;
        const int ry = ny + 1;
        const int rx = nx + 1;
        const float c = sxp[ry][rx];
        float prod;
        prod  = fmaxf(c - sxp[ry - 1][rx - 1], 0.f);
        prod *= fmaxf(c - sxp[ry - 1][rx    ], 0.f);
        prod *= fmaxf(c - sxp[ry - 1][rx + 1], 0.f);
        prod *= fmaxf(c - sxp[ry    ][rx - 1], 0.f);
        prod *= fmaxf(c - sxp[ry    ][rx + 1], 0.f);
        prod *= fmaxf(c - sxp[ry + 1][rx - 1], 0.f);
        prod *= fmaxf(c - sxp[ry + 1][rx    ], 0.f);
        prod *= fmaxf(c - sxp[ry + 1][rx + 1], 0.f);
        snm[ny][nx] = prod * 256.f;
    }
    __syncthreads();

    // Phase 3: 3x3 max pool of xNMS, multiply by xp, store.
    float* __restrict__ po = out + (size_t)b * Hd * Wd;
    for (int idx = tid; idx < TY * TX; idx += 256) {
        const int ty = idx / TX;
        const int tx = idx - ty * TX;
        // snm center for output (ty,tx) is snm[ty+1][tx+1]
        float m;
        m = snm[ty    ][tx    ];
        m = fmaxf(m, snm[ty    ][tx + 1]);
        m = fmaxf(m, snm[ty    ][tx + 2]);
        m = fmaxf(m, snm[ty + 1][tx    ]);
        m = fmaxf(m, snm[ty + 1][tx + 1]);
        m = fmaxf(m, snm[ty + 1][tx + 2]);
        m = fmaxf(m, snm[ty + 2][tx    ]);
        m = fmaxf(m, snm[ty + 2][tx + 1]);
        m = fmaxf(m, snm[ty + 2][tx + 2]);
        const float c = sxp[ty + 2][tx + 2];
        po[(size_t)(y0 + ty) * Wd + (x0 + tx)] = c * m;
    }
}

extern "C" void kernel_launch(void* const* d_in, const int* in_sizes, int n_in,
                              void* d_out, int out_size, void* d_ws, size_t ws_size,
                              hipStream_t stream) {
    const float* xin = (const float*)d_in[0];
    float* out = (float*)d_out;
    dim3 grid(Wd / TX, Hd / TY, Bd);
    hardnms_kernel<<<grid, dim3(256), 0, stream>>>(xin, out);
}